// Round 1
// baseline (305.298 us; speedup 1.0000x reference)
//
#include <hip/hip_runtime.h>

#define L_LEN 32768
#define IC 64
#define OC 64
#define KW 3
#define BS 8
#define JN (IC*KW)          // 192
#define QMAXF 127.0f

// ws float layout:
// [0..192)    w_scale
// [192..384)  act3 (atomicMax targets; zeroed each launch)
// [384..576)  scale
// [576]=s_x [577]=s_w [578]=s_x*s_w
// [640..640+12288) qw_t  [j][oc]  (integer-valued floats, -127..127)

__global__ void wscale_kernel(const float* __restrict__ w, float* __restrict__ ws) {
    int j = threadIdx.x;            // 0..191
    float m = 0.0f;
    for (int o = 0; o < OC; ++o) m = fmaxf(m, fabsf(w[o*JN + j]));
    ws[j] = m;
}

__global__ __launch_bounds__(256) void actamax_kernel(const float* __restrict__ x,
                                                      float* __restrict__ ws) {
    const int ic = blockIdx.x, b = blockIdx.y;
    const float4* row = (const float4*)(x + ((size_t)(b*IC + ic) << 15));
    const int NF4 = L_LEN >> 2;     // 8192
    float mA = 0.0f, mNF = 0.0f, mNL = 0.0f;   // all, no-first(t>0), no-last(t<L-1)
    for (int f = threadIdx.x; f < NF4; f += 256) {
        float4 v = row[f];
        float ax = fabsf(v.x), ay = fabsf(v.y), az = fabsf(v.z), aw = fabsf(v.w);
        float m4 = fmaxf(fmaxf(ax, ay), fmaxf(az, aw));
        mA = fmaxf(mA, m4);
        if (f == 0) {
            mNF = fmaxf(mNF, fmaxf(ay, fmaxf(az, aw)));
            mNL = fmaxf(mNL, m4);
        } else if (f == NF4 - 1) {
            mNF = fmaxf(mNF, m4);
            mNL = fmaxf(mNL, fmaxf(ax, fmaxf(ay, az)));
        } else {
            mNF = fmaxf(mNF, m4);
            mNL = fmaxf(mNL, m4);
        }
    }
    #pragma unroll
    for (int off = 32; off; off >>= 1) {
        mA  = fmaxf(mA,  __shfl_down(mA,  off));
        mNF = fmaxf(mNF, __shfl_down(mNF, off));
        mNL = fmaxf(mNL, __shfl_down(mNL, off));
    }
    __shared__ float red[3][4];
    int wid = threadIdx.x >> 6;
    if ((threadIdx.x & 63) == 0) { red[0][wid] = mA; red[1][wid] = mNF; red[2][wid] = mNL; }
    __syncthreads();
    if (threadIdx.x == 0) {
        mA  = fmaxf(fmaxf(red[0][0], red[0][1]), fmaxf(red[0][2], red[0][3]));
        mNF = fmaxf(fmaxf(red[1][0], red[1][1]), fmaxf(red[1][2], red[1][3]));
        mNL = fmaxf(fmaxf(red[2][0], red[2][1]), fmaxf(red[2][2], red[2][3]));
        // k=0: x[-1..L-2] -> exclude last; k=1: all; k=2: x[1..L] -> exclude first
        atomicMax((unsigned int*)&ws[192 + ic*3 + 0], __float_as_uint(mNL));
        atomicMax((unsigned int*)&ws[192 + ic*3 + 1], __float_as_uint(mA));
        atomicMax((unsigned int*)&ws[192 + ic*3 + 2], __float_as_uint(mNF));
    }
}

__global__ __launch_bounds__(256) void finalize_kernel(const float* __restrict__ w,
                                                       float* __restrict__ ws) {
    __shared__ float2 red[256];
    __shared__ float ssw;
    const int tid = threadIdx.x;
    float ax = 0.0f, aw = 0.0f;
    if (tid < JN) {
        float wsc = ws[tid];
        float asc = ws[192 + tid];
        float sc = sqrtf(asc) / sqrtf(wsc);    // mirrors act**0.5 / w**0.5
        if (sc == 0.0f) sc = 1.0f;
        ws[384 + tid] = sc;
        ax = asc / sc;    // == max_j |cols/scale| column max (monotone fp div)
        aw = wsc * sc;    // == max_oc |w*scale|
    }
    red[tid] = make_float2(ax, aw);
    __syncthreads();
    for (int s = 128; s; s >>= 1) {
        if (tid < s) {
            red[tid].x = fmaxf(red[tid].x, red[tid + s].x);
            red[tid].y = fmaxf(red[tid].y, red[tid + s].y);
        }
        __syncthreads();
    }
    if (tid == 0) {
        float axm = red[0].x, awm = red[0].y;
        float s_x = (axm == 0.0f) ? 1.0f : axm / QMAXF;
        float s_w = (awm == 0.0f) ? 1.0f : awm / QMAXF;
        ws[576] = s_x; ws[577] = s_w; ws[578] = s_x * s_w;
        ssw = s_w;
    }
    __syncthreads();
    const float s_w = ssw;
    // quantized weights, transposed: qw_t[j*64 + oc]
    for (int idx = tid; idx < OC*JN; idx += 256) {
        int oc = idx & 63, j = idx >> 6;
        float sc = ws[384 + j];
        float t = w[oc*JN + j] * sc;
        float q = rintf(t / s_w);
        q = fminf(fmaxf(q, -QMAXF), QMAXF);
        ws[640 + idx] = q;
    }
}

// Conv: one block = 64 output positions x all 64 OC, one batch.
// LDS: 3 shifted quantized x planes [k][ic][64] + scale copy; out tile aliases planes.
__global__ __launch_bounds__(256) void conv_kernel(const float* __restrict__ x,
                                                   const float* __restrict__ bias,
                                                   const float* __restrict__ ws,
                                                   float* __restrict__ out) {
    __shared__ float smem[12288 + 192];
    float* xqs = smem;              // [3][64][64]
    float* scl = smem + 12288;      // [192]
    const int b  = blockIdx.y;
    const int t0 = blockIdx.x << 6;
    const int tid = threadIdx.x;

    if (tid < JN) scl[tid] = ws[384 + tid];
    __syncthreads();
    const float s_x = ws[576];

    // stage + quantize x tile: element off covers t = t0-1 .. t0+64
    for (int idx = tid; idx < IC*66; idx += 256) {
        int ic  = idx / 66;
        int off = idx - ic*66;
        int t = t0 + off - 1;
        float xv = 0.0f;
        if (t >= 0 && t < L_LEN) xv = x[((size_t)(b*IC + ic) << 15) + t];
        #pragma unroll
        for (int k = 0; k < 3; ++k) {
            int j = off - k;
            if ((unsigned)j < 64u) {
                float sc = scl[ic*3 + k];
                float q = rintf((xv / sc) / s_x);   // exact ref op order
                q = fminf(fmaxf(q, -QMAXF), QMAXF);
                xqs[((k*IC + ic) << 6) + j] = q;
            }
        }
    }
    __syncthreads();

    const int oc = tid & 63;
    const int tg = tid >> 6;        // wave-uniform -> LDS reads broadcast
    const float* qt = ws + 640;
    float acc[16];
    #pragma unroll
    for (int i = 0; i < 16; ++i) acc[i] = 0.0f;

    for (int ic = 0; ic < IC; ++ic) {
        float w0 = qt[(ic*3 + 0)*64 + oc];   // coalesced 256B, L2-resident
        float w1 = qt[(ic*3 + 1)*64 + oc];
        float w2 = qt[(ic*3 + 2)*64 + oc];
        const float4* x0 = (const float4*)(xqs + ((0*IC + ic) << 6) + (tg << 4));
        const float4* x1 = (const float4*)(xqs + ((1*IC + ic) << 6) + (tg << 4));
        const float4* x2 = (const float4*)(xqs + ((2*IC + ic) << 6) + (tg << 4));
        #pragma unroll
        for (int q4 = 0; q4 < 4; ++q4) {
            float4 a = x0[q4];
            acc[q4*4+0] += w0*a.x; acc[q4*4+1] += w0*a.y;
            acc[q4*4+2] += w0*a.z; acc[q4*4+3] += w0*a.w;
        }
        #pragma unroll
        for (int q4 = 0; q4 < 4; ++q4) {
            float4 a = x1[q4];
            acc[q4*4+0] += w1*a.x; acc[q4*4+1] += w1*a.y;
            acc[q4*4+2] += w1*a.z; acc[q4*4+3] += w1*a.w;
        }
        #pragma unroll
        for (int q4 = 0; q4 < 4; ++q4) {
            float4 a = x2[q4];
            acc[q4*4+0] += w2*a.x; acc[q4*4+1] += w2*a.y;
            acc[q4*4+2] += w2*a.z; acc[q4*4+3] += w2*a.w;
        }
    }

    __syncthreads();                 // done reading xqs; reuse as out tile
    const float sxw = ws[578];
    const float bv = bias[oc];
    float* ot = smem;                // [64][65]
    #pragma unroll
    for (int i = 0; i < 16; ++i)
        ot[oc*65 + tg*16 + i] = acc[i]*sxw + bv;
    __syncthreads();
    for (int idx = tid; idx < OC*64; idx += 256) {
        int o = idx >> 6, p = idx & 63;
        out[((size_t)(b*OC + o) << 15) + t0 + p] = ot[o*65 + p];
    }
}

extern "C" void kernel_launch(void* const* d_in, const int* in_sizes, int n_in,
                              void* d_out, int out_size, void* d_ws, size_t ws_size,
                              hipStream_t stream) {
    const float* x    = (const float*)d_in[0];
    const float* w    = (const float*)d_in[1];
    const float* bias = (const float*)d_in[2];
    float* out = (float*)d_out;
    float* ws  = (float*)d_ws;

    hipMemsetAsync(ws, 0, 2560, stream);   // zero w_scale..scalars incl. act3 atomics
    hipLaunchKernelGGL(wscale_kernel,  dim3(1),        dim3(192), 0, stream, w, ws);
    hipLaunchKernelGGL(actamax_kernel, dim3(IC, BS),   dim3(256), 0, stream, x, ws);
    hipLaunchKernelGGL(finalize_kernel,dim3(1),        dim3(256), 0, stream, w, ws);
    hipLaunchKernelGGL(conv_kernel,    dim3(512, BS),  dim3(256), 0, stream, x, bias, ws, out);
}

// Round 2
// 172.081 us; speedup vs baseline: 1.7742x; 1.7742x over previous
//
#include <hip/hip_runtime.h>

#define L_LEN 32768
#define QMAXF 127.0f

typedef __attribute__((ext_vector_type(4))) int v4i;

// ws layout:
//   float[0..192)    : act3 per-(ic,k) abs-max (atomicMax targets, memset to 0)
//   float[192..384)  : r_j = 1/(scale_j * s_x)
//   float[384]       : s_x * s_w
//   byte offset 2048 : A fragments (quantized weights, i8, MFMA lane-chunk order), 12288 B

__global__ __launch_bounds__(256) void actamax_kernel(const float* __restrict__ x,
                                                      float* __restrict__ ws) {
    const int ic = blockIdx.x, b = blockIdx.y;
    const float4* row = (const float4*)(x + ((size_t)(b*64 + ic) << 15));
    const int NF4 = L_LEN >> 2;
    float mA = 0.0f, mNF = 0.0f, mNL = 0.0f;   // all, no-first(t>0), no-last(t<L-1)
    for (int f = threadIdx.x; f < NF4; f += 256) {
        float4 v = row[f];
        float ax = fabsf(v.x), ay = fabsf(v.y), az = fabsf(v.z), aw = fabsf(v.w);
        float m4 = fmaxf(fmaxf(ax, ay), fmaxf(az, aw));
        mA = fmaxf(mA, m4);
        if (f == 0) {
            mNF = fmaxf(mNF, fmaxf(ay, fmaxf(az, aw)));
            mNL = fmaxf(mNL, m4);
        } else if (f == NF4 - 1) {
            mNF = fmaxf(mNF, m4);
            mNL = fmaxf(mNL, fmaxf(ax, fmaxf(ay, az)));
        } else {
            mNF = fmaxf(mNF, m4);
            mNL = fmaxf(mNL, m4);
        }
    }
    #pragma unroll
    for (int off = 32; off; off >>= 1) {
        mA  = fmaxf(mA,  __shfl_down(mA,  off));
        mNF = fmaxf(mNF, __shfl_down(mNF, off));
        mNL = fmaxf(mNL, __shfl_down(mNL, off));
    }
    __shared__ float red[3][4];
    int wid = threadIdx.x >> 6;
    if ((threadIdx.x & 63) == 0) { red[0][wid] = mA; red[1][wid] = mNF; red[2][wid] = mNL; }
    __syncthreads();
    if (threadIdx.x == 0) {
        mA  = fmaxf(fmaxf(red[0][0], red[0][1]), fmaxf(red[0][2], red[0][3]));
        mNF = fmaxf(fmaxf(red[1][0], red[1][1]), fmaxf(red[1][2], red[1][3]));
        mNL = fmaxf(fmaxf(red[2][0], red[2][1]), fmaxf(red[2][2], red[2][3]));
        // k=0 uses x[-1..L-2] -> exclude last; k=1 all; k=2 uses x[1..L] -> exclude first
        atomicMax((unsigned int*)&ws[ic*3 + 0], __float_as_uint(mNL));
        atomicMax((unsigned int*)&ws[ic*3 + 1], __float_as_uint(mA));
        atomicMax((unsigned int*)&ws[ic*3 + 2], __float_as_uint(mNF));
    }
}

// One block: w_scale, scales, s_x/s_w, reciprocals, weight-quant into A-fragment order.
__global__ __launch_bounds__(256) void prep_kernel(const float* __restrict__ w,
                                                   float* __restrict__ wsf,
                                                   unsigned int* __restrict__ wsa) {
    __shared__ float scl[192];
    __shared__ float red[256];
    const int tid = threadIdx.x;
    float ax = 0.0f, aw = 0.0f, wsc = 0.0f;
    if (tid < 192) {
        #pragma unroll 8
        for (int o = 0; o < 64; ++o) wsc = fmaxf(wsc, fabsf(w[o*192 + tid]));
        float asc = wsf[tid];                     // act abs-max from atomics
        float sc = sqrtf(asc) / sqrtf(wsc);       // act**0.5 / w**0.5
        if (sc == 0.0f) sc = 1.0f;
        scl[tid] = sc;
        ax = asc / sc;                            // column max of |cols/scale| (monotone)
        aw = wsc * sc;                            // max |w*scale|
    }
    red[tid] = ax; __syncthreads();
    for (int s = 128; s; s >>= 1) { if (tid < s) red[tid] = fmaxf(red[tid], red[tid+s]); __syncthreads(); }
    float axm = red[0]; __syncthreads();
    red[tid] = aw; __syncthreads();
    for (int s = 128; s; s >>= 1) { if (tid < s) red[tid] = fmaxf(red[tid], red[tid+s]); __syncthreads(); }
    float awm = red[0];
    float s_x = (axm == 0.0f) ? 1.0f : axm / QMAXF;
    float s_w = (awm == 0.0f) ? 1.0f : awm / QMAXF;
    if (tid < 192) wsf[192 + tid] = 1.0f / (scl[tid] * s_x);
    if (tid == 0) wsf[384] = s_x * s_w;
    __syncthreads();
    // quantize weights into MFMA A-fragment (16x16x64 i8) lane-chunk order
    for (int idx = tid; idx < 3072; idx += 256) {
        int oc = idx / 48, dwi = idx - oc*48, j0 = dwi*4;
        unsigned pk = 0;
        #pragma unroll
        for (int bb = 0; bb < 4; ++bb) {
            int j = j0 + bb;
            float q = rintf((w[oc*192 + j] * scl[j]) / s_w);  // ref op order
            q = fminf(fmaxf(q, -QMAXF), QMAXF);
            pk |= (((unsigned)(int)q) & 255u) << (8*bb);
        }
        int mt = oc >> 4, m = oc & 15, c = j0 >> 4, s = c >> 2, kq = c & 3;
        wsa[((mt*3 + s)*64 + kq*16 + m)*4 + ((j0 & 15) >> 2)] = pk;
    }
}

// Conv as i8 MFMA GEMM: D[oc][t] = sum_j qw[oc][j] * qx[j][t], j = ic*3+k.
// Block: 64 t x 64 oc x 1 batch; 4 waves, wave w owns t-range [16w,16w+16).
__global__ __launch_bounds__(256) void conv_mfma_kernel(const float* __restrict__ x,
                                                        const float* __restrict__ bias,
                                                        const float* __restrict__ wsf,
                                                        const v4i* __restrict__ wsa,
                                                        float* __restrict__ out) {
    __shared__ int bsm[3072];   // B fragments: [wave][3 ksteps][64 lanes][16 B]
    const int tid  = threadIdx.x;
    const int b    = blockIdx.y;
    const int t0   = blockIdx.x << 6;
    const int lane = tid & 63;
    const int w    = tid >> 6;

    // A fragments: 4 m-tiles x 3 k-steps, 16 B/lane each (precomputed order)
    v4i afrag[12];
    #pragma unroll
    for (int i = 0; i < 12; ++i) afrag[i] = wsa[i*64 + lane];

    // ---- stage + quantize x into B-fragment-sequential LDS ----
    const int tq  = tid & 15;      // owns t = 4*tq .. 4*tq+3 (block-local)
    const int icg = tid >> 4;      // owns ic = 4*icg .. 4*icg+3  (j = 12*icg..+11)
    const int tb  = tq << 2;

    float rv[12];
    #pragma unroll
    for (int jj = 0; jj < 12; ++jj) rv[jj] = wsf[192 + icg*12 + jj];

    float xv[4][6];                // [ici][t-1 .. t+4]
    #pragma unroll
    for (int ici = 0; ici < 4; ++ici) {
        const float* row = x + (((size_t)(b*64 + icg*4 + ici)) << 15) + t0 + tb;
        float4 mid = *(const float4*)row;
        float lm = (t0 + tb > 0)           ? row[-1] : 0.0f;
        float rp = (t0 + tb + 4 < L_LEN)   ? row[4]  : 0.0f;
        xv[ici][0] = lm;   xv[ici][1] = mid.x; xv[ici][2] = mid.y;
        xv[ici][3] = mid.z; xv[ici][4] = mid.w; xv[ici][5] = rp;
    }

    #pragma unroll
    for (int dt = 0; dt < 4; ++dt) {
        int t  = tb + dt;
        int wt = t >> 4, n = t & 15;
        #pragma unroll
        for (int dw = 0; dw < 3; ++dw) {
            unsigned pk = 0;
            #pragma unroll
            for (int bb = 0; bb < 4; ++bb) {
                int jloc = dw*4 + bb;           // 0..11 ; j = 12*icg + jloc = 3*ic + k
                int ici = jloc / 3, k = jloc - ici*3;
                float q = rintf(xv[ici][dt + k] * rv[jloc]);
                q = fminf(fmaxf(q, -QMAXF), QMAXF);
                pk |= (((unsigned)(int)q) & 255u) << (8*bb);
            }
            int j0 = icg*12 + dw*4;
            int c = j0 >> 4, s = c >> 2, kq = c & 3;
            bsm[((wt*3 + s)*64 + kq*16 + n)*4 + ((j0 & 15) >> 2)] = (int)pk;
        }
    }
    __syncthreads();

    // ---- MFMA ----
    v4i acc[4];
    #pragma unroll
    for (int mt = 0; mt < 4; ++mt) acc[mt] = (v4i){0,0,0,0};
    const v4i* bsmv = (const v4i*)bsm;
    #pragma unroll
    for (int s = 0; s < 3; ++s) {
        v4i bf = bsmv[(w*3 + s)*64 + lane];
        #pragma unroll
        for (int mt = 0; mt < 4; ++mt)
            acc[mt] = __builtin_amdgcn_mfma_i32_16x16x64_i8(afrag[mt*3 + s], bf, acc[mt], 0, 0, 0);
    }

    // ---- epilogue: C/D layout col=lane&15 -> t, row=(lane>>4)*4+i -> oc ----
    const float sxw = wsf[384];
    const int tg   = t0 + (w << 4) + (lane & 15);
    const int rowq = (lane >> 4) << 2;
    #pragma unroll
    for (int mt = 0; mt < 4; ++mt) {
        #pragma unroll
        for (int i = 0; i < 4; ++i) {
            int oc = mt*16 + rowq + i;
            out[(((size_t)(b*64 + oc)) << 15) + tg] = (float)acc[mt][i] * sxw + bias[oc];
        }
    }
}

extern "C" void kernel_launch(void* const* d_in, const int* in_sizes, int n_in,
                              void* d_out, int out_size, void* d_ws, size_t ws_size,
                              hipStream_t stream) {
    const float* x    = (const float*)d_in[0];
    const float* w    = (const float*)d_in[1];
    const float* bias = (const float*)d_in[2];
    float* out = (float*)d_out;
    float* wsf = (float*)d_ws;
    unsigned int* wsa = (unsigned int*)((char*)d_ws + 2048);

    hipMemsetAsync(d_ws, 0, 768, stream);   // zero act3 atomic targets
    hipLaunchKernelGGL(actamax_kernel,  dim3(64, 8),  dim3(256), 0, stream, x, wsf);
    hipLaunchKernelGGL(prep_kernel,     dim3(1),      dim3(256), 0, stream, w, wsf, wsa);
    hipLaunchKernelGGL(conv_mfma_kernel,dim3(512, 8), dim3(256), 0, stream, x, bias, wsf, (const v4i*)wsa, out);
}